// Round 4
// baseline (353.001 us; speedup 1.0000x reference)
//
#include <hip/hip_runtime.h>

typedef unsigned short u16;
typedef short bf16x8 __attribute__((ext_vector_type(8)));
typedef float f32x4 __attribute__((ext_vector_type(4)));

#define CH 512
#define HW 4096
#define TOKENS 16384
#define NGRP 32

__device__ __forceinline__ u16 f2bf(float f) {
  unsigned u = __float_as_uint(f);
  u += 0x7fffu + ((u >> 16) & 1u);   // round-nearest-even
  return (u16)(u >> 16);
}
__device__ __forceinline__ float bf2f(u16 h) {
  return __uint_as_float(((unsigned)h) << 16);
}

// async global->LDS, 16B per lane; lds base must be wave-uniform
#define GLOAD16(gp, lp)                                                        \
  __builtin_amdgcn_global_load_lds(                                            \
      (const __attribute__((address_space(1))) unsigned int*)(const void*)(gp),\
      (__attribute__((address_space(3))) unsigned int*)(void*)(lp), 16, 0, 0)

// ---------------- GroupNorm stats: one block per (b,g) ----------------
__global__ void gn_stats(const float* __restrict__ x, float2* __restrict__ stats) {
  int bg = blockIdx.x;              // 0..127
  int b = bg >> 5, g = bg & 31;
  const float* base = x + (size_t)b * HW * CH + g * 16;
  float s = 0.f, s2 = 0.f;
  for (int p = threadIdx.x; p < HW; p += 256) {
    const float4* row = (const float4*)(base + (size_t)p * CH);
#pragma unroll
    for (int q = 0; q < 4; ++q) {
      float4 v = row[q];
      s += v.x + v.y + v.z + v.w;
      s2 += v.x * v.x + v.y * v.y + v.z * v.z + v.w * v.w;
    }
  }
#pragma unroll
  for (int o = 32; o; o >>= 1) { s += __shfl_down(s, o); s2 += __shfl_down(s2, o); }
  __shared__ float rs[4], rs2[4];
  int wid = threadIdx.x >> 6, lane = threadIdx.x & 63;
  if (lane == 0) { rs[wid] = s; rs2[wid] = s2; }
  __syncthreads();
  if (threadIdx.x == 0) {
    float S = rs[0] + rs[1] + rs[2] + rs[3];
    float S2 = rs2[0] + rs2[1] + rs2[2] + rs2[3];
    float mean = S * (1.f / 65536.f);
    float var = S2 * (1.f / 65536.f) - mean * mean;
    stats[bg] = make_float2(mean, rsqrtf(var + 1e-5f));
  }
}

// ---------------- GroupNorm apply -> xn (bf16) ----------------
__global__ void gn_apply(const float* __restrict__ x, const float* __restrict__ gamma,
                         const float* __restrict__ beta, const float2* __restrict__ stats,
                         u16* __restrict__ xn) {
  size_t i = (size_t)blockIdx.x * blockDim.x + threadIdx.x;  // chunk of 8 elems
  size_t e0 = i * 8;
  int c = (int)(e0 & (CH - 1));
  size_t t = e0 >> 9;
  int b = (int)(t >> 12);
  float2 st = stats[b * NGRP + (c >> 4)];
  float4 v0 = *(const float4*)(x + t * CH + c);
  float4 v1 = *(const float4*)(x + t * CH + c + 4);
  float4 g0 = *(const float4*)(gamma + c);
  float4 g1 = *(const float4*)(gamma + c + 4);
  float4 b0 = *(const float4*)(beta + c);
  float4 b1 = *(const float4*)(beta + c + 4);
  float o[8];
  o[0] = (v0.x - st.x) * st.y * g0.x + b0.x;
  o[1] = (v0.y - st.x) * st.y * g0.y + b0.y;
  o[2] = (v0.z - st.x) * st.y * g0.z + b0.z;
  o[3] = (v0.w - st.x) * st.y * g0.w + b0.w;
  o[4] = (v1.x - st.x) * st.y * g1.x + b1.x;
  o[5] = (v1.y - st.x) * st.y * g1.y + b1.y;
  o[6] = (v1.z - st.x) * st.y * g1.z + b1.z;
  o[7] = (v1.w - st.x) * st.y * g1.w + b1.w;
  union { u16 us[8]; uint4 q; } pk;
#pragma unroll
  for (int k = 0; k < 8; ++k) pk.us[k] = f2bf(o[k]);
  *(uint4*)(xn + e0) = pk.q;
}

// ---------------- transpose 512x512 weights fp32 -> bf16 (T[d][c] = W[c][d]) ----------------
__global__ void transpose_w(const float* __restrict__ W0, const float* __restrict__ W1,
                            const float* __restrict__ W2, const float* __restrict__ W3,
                            u16* __restrict__ T0, u16* __restrict__ T1,
                            u16* __restrict__ T2, u16* __restrict__ T3) {
  const float* W; u16* T;
  switch (blockIdx.z) {
    case 0: W = W0; T = T0; break;
    case 1: W = W1; T = T1; break;
    case 2: W = W2; T = T2; break;
    default: W = W3; T = T3; break;
  }
  __shared__ float tile[32][33];
  int tx = threadIdx.x, ty = threadIdx.y;
  int x0 = blockIdx.x * 32, y0 = blockIdx.y * 32;
#pragma unroll
  for (int r = 0; r < 32; r += 8) tile[ty + r][tx] = W[(size_t)(y0 + ty + r) * CH + x0 + tx];
  __syncthreads();
#pragma unroll
  for (int r = 0; r < 32; r += 8) T[(size_t)(x0 + ty + r) * CH + y0 + tx] = f2bf(tile[tx][ty + r]);
}

// ---- m97-structure NT GEMM: C[M,N] = scale * A[M,K] * Bt[N,K]^T, global_load_lds staging ----
// 128x128 tile, BK=64, 4 waves (2x2), per-wave 4x4 frags of 16x16x32.
// MODE 2: f32 out + residual add (proj)
// MODE 3: fused QKV epilogue (N=1536; chunk 0->Cout, 1->C2 rowmajor, 2->C3 V-layout)
// MODE 4: PV: divide by lsum[z*HW+row]; XCD-swizzled 1-D grid when gridDim.y==1
// MODE 5: S-GEMM: exp() epilogue + rowsum atomicAdd into lsum
template <int MODE>
__global__ __launch_bounds__(256) void gemm97(const u16* __restrict__ A,
                                              const u16* __restrict__ Bt,
                                              const float* __restrict__ bias,
                                              const float* __restrict__ bias2,
                                              const float* __restrict__ bias3,
                                              const float* __restrict__ residual,
                                              float* __restrict__ lsum,
                                              void* __restrict__ Cout,
                                              void* __restrict__ C2,
                                              void* __restrict__ C3,
                                              int M, int N, int K, float scale,
                                              size_t sA, size_t sB, size_t sC) {
  constexpr int BM = 128, BN = 128, BK = 64;
  __shared__ __align__(16) u16 lA[BM * BK];
  __shared__ __align__(16) u16 lB[BN * BK];

  int bm, bn, z;
  if constexpr (MODE == 4) {
    if (gridDim.y == 1) {             // big path: 512 blocks, XCD-chunked swizzle
      int p = blockIdx.x;
      int xcd = p & 7, j = p >> 3;    // j: 0..63 per XCD
      int xi = j & 3;                 // 4 consecutive same-XCD blocks share m-panel
      int mp = xcd * 16 + (j >> 2);   // global m-panel 0..127
      bn = xi * BN; bm = (mp & 31) * BM; z = mp >> 5;
    } else {
      z = blockIdx.z; bm = blockIdx.y * BM; bn = blockIdx.x * BN;
    }
  } else {
    z = blockIdx.z; bm = blockIdx.y * BM; bn = blockIdx.x * BN;
  }
  A += (size_t)z * sA;
  Bt += (size_t)z * sB;

  const int tid = threadIdx.x;
  const int lane = tid & 63, wid = tid >> 6;
  const int wm = (wid >> 1) * 64, wn = (wid & 1) * 64;
  const int r0 = lane & 15, h = lane >> 4;

  // staging geometry: wave wid, issue s stages 8 rows x 64 cols (1 KB) of each tile
  const int srow = lane >> 3, scol = (lane & 7) * 8;
  size_t aoff[4], boff[4];
#pragma unroll
  for (int s = 0; s < 4; ++s) {
    int row = (wid * 4 + s) * 8 + srow;
    aoff[s] = (size_t)(bm + row) * K + scol;
    boff[s] = (size_t)(bn + row) * K + scol;
  }

  f32x4 acc[4][4] = {};

  for (int kt = 0; kt < K; kt += BK) {
    __syncthreads();
#pragma unroll
    for (int s = 0; s < 4; ++s) {
      GLOAD16(A + aoff[s] + kt, &lA[(wid * 4 + s) * 512]);
      GLOAD16(Bt + boff[s] + kt, &lB[(wid * 4 + s) * 512]);
    }
    __syncthreads();
#pragma unroll
    for (int kk = 0; kk < BK; kk += 32) {
      bf16x8 af[4], bfr[4];
#pragma unroll
      for (int i = 0; i < 4; ++i)
        af[i] = *(const bf16x8*)(&lA[(wm + i * 16 + r0) * BK + kk + h * 8]);
#pragma unroll
      for (int j = 0; j < 4; ++j)
        bfr[j] = *(const bf16x8*)(&lB[(wn + j * 16 + r0) * BK + kk + h * 8]);
#pragma unroll
      for (int i = 0; i < 4; ++i)
#pragma unroll
        for (int j = 0; j < 4; ++j)
          acc[i][j] = __builtin_amdgcn_mfma_f32_16x16x32_bf16(af[i], bfr[j], acc[i][j], 0, 0, 0);
    }
  }

  // epilogue: D layout col = lane&15 (n), row = (lane>>4)*4 + r
  if constexpr (MODE == 5) {
    float rsum[4][4];                  // [i][r], summed over j then over 16 lanes
#pragma unroll
    for (int i = 0; i < 4; ++i)
#pragma unroll
      for (int r = 0; r < 4; ++r) rsum[i][r] = 0.f;
    u16* C = (u16*)Cout + (size_t)z * sC;
#pragma unroll
    for (int j = 0; j < 4; ++j) {
      int n = bn + wn + j * 16 + r0;
#pragma unroll
      for (int i = 0; i < 4; ++i) {
        int m0 = bm + wm + i * 16 + h * 4;
#pragma unroll
        for (int r = 0; r < 4; ++r) {
          float e = __expf(acc[i][j][r] * scale);
          rsum[i][r] += e;
          C[(size_t)(m0 + r) * N + n] = f2bf(e);
        }
      }
    }
#pragma unroll
    for (int i = 0; i < 4; ++i)
#pragma unroll
      for (int r = 0; r < 4; ++r) {
#pragma unroll
        for (int w = 1; w < 16; w <<= 1) rsum[i][r] += __shfl_xor(rsum[i][r], w);
        if (r0 == 0)
          atomicAdd(&lsum[z * HW + bm + wm + i * 16 + h * 4 + r], rsum[i][r]);
      }
  } else {
#pragma unroll
    for (int j = 0; j < 4; ++j) {
      int n = bn + wn + j * 16 + r0;
      float bvv;
      if constexpr (MODE == 3) {
        int nn = n & 511, ch = n >> 9;
        bvv = ch == 0 ? bias[nn] : ch == 1 ? bias2[nn] : bias3[nn];
      } else {
        bvv = bias ? bias[n] : 0.0f;
      }
#pragma unroll
      for (int i = 0; i < 4; ++i) {
        int m0 = bm + wm + i * 16 + h * 4;
        float v[4];
#pragma unroll
        for (int r = 0; r < 4; ++r) v[r] = acc[i][j][r] * scale + bvv;
        if constexpr (MODE == 2) {
          float* C = (float*)Cout + (size_t)z * sC;
#pragma unroll
          for (int r = 0; r < 4; ++r) {
            size_t idx = (size_t)(m0 + r) * N + n;
            C[idx] = v[r] + residual[idx];
          }
        } else if constexpr (MODE == 3) {
          int nn = n & 511, ch = n >> 9;
          if (ch == 2) {                // V: transposed layout [bb][CH][HW]
            int bb = m0 >> 12, tl = m0 & (HW - 1);
            u16* C = (u16*)C3 + ((size_t)bb * CH + nn) * HW + tl;
            union { u16 us[4]; uint2 q; } pk;
#pragma unroll
            for (int r = 0; r < 4; ++r) pk.us[r] = f2bf(v[r]);
            *(uint2*)C = pk.q;
          } else {
            u16* C = (u16*)(ch == 0 ? Cout : C2);
#pragma unroll
            for (int r = 0; r < 4; ++r) C[(size_t)(m0 + r) * CH + nn] = f2bf(v[r]);
          }
        } else {                        // MODE 4: PV, divide by row sum
          u16* C = (u16*)Cout + (size_t)z * sC;
#pragma unroll
          for (int r = 0; r < 4; ++r) {
            float inv = 1.0f / lsum[z * HW + m0 + r];
            C[(size_t)(m0 + r) * N + n] = f2bf(v[r] * inv);
          }
        }
      }
    }
  }
}

extern "C" void kernel_launch(void* const* d_in, const int* in_sizes, int n_in,
                              void* d_out, int out_size, void* d_ws, size_t ws_size,
                              hipStream_t stream) {
  (void)in_sizes; (void)n_in; (void)out_size;
  const float* x     = (const float*)d_in[0];
  const float* gamma = (const float*)d_in[1];
  const float* beta  = (const float*)d_in[2];
  const float* Wq    = (const float*)d_in[3];
  const float* bq    = (const float*)d_in[4];
  const float* Wk    = (const float*)d_in[5];
  const float* bk    = (const float*)d_in[6];
  const float* Wv    = (const float*)d_in[7];
  const float* bv    = (const float*)d_in[8];
  const float* Wp    = (const float*)d_in[9];
  const float* bp    = (const float*)d_in[10];
  float* out = (float*)d_out;

  char* ws = (char*)d_ws;
  size_t off = 0;
  auto alloc = [&](size_t bytes) -> void* {
    void* p = ws + off;
    off += (bytes + 255) & ~(size_t)255;
    return p;
  };
  const size_t XN = (size_t)TOKENS * CH * 2;      // 16 MB
  const size_t WT = (size_t)CH * CH * 2;          // 0.5 MB
  const size_t SBB = (size_t)HW * HW * 2;         // 33.5 MB per batch
  const size_t need_all = 1024 * 1024 + 5 * XN + 4 * WT + 4 * SBB;
  const bool big = ws_size >= need_all;           // deterministic across calls

  float2* stats = (float2*)alloc(128 * sizeof(float2));
  float* lsum  = (float*)alloc(4 * HW * sizeof(float));
  u16* xn   = (u16*)alloc(XN);
  u16* Qb   = (u16*)alloc(XN);
  u16* Kb   = (u16*)alloc(XN);
  u16* Vt   = (u16*)alloc(XN);   // [B][CH][HW]
  u16* Ob   = (u16*)alloc(XN);
  u16* Wqkv = (u16*)alloc(3 * WT);  // [Wq^T; Wk^T; Wv^T] stacked along rows
  u16* WpT  = (u16*)alloc(WT);
  u16* Sb   = (u16*)alloc(big ? 4 * SBB : SBB);   // exp'd scores

  hipMemsetAsync(lsum, 0, 4 * HW * sizeof(float), stream);
  gn_stats<<<128, 256, 0, stream>>>(x, stats);
  gn_apply<<<TOKENS * CH / 8 / 256, 256, 0, stream>>>(x, gamma, beta, stats, xn);
  transpose_w<<<dim3(16, 16, 4), dim3(32, 8), 0, stream>>>(
      Wq, Wk, Wv, Wp, Wqkv, Wqkv + (size_t)CH * CH, Wqkv + 2 * (size_t)CH * CH, WpT);

  // fused QKV: one GEMM, N=1536, epilogue routes chunks
  gemm97<3><<<dim3(1536 / 128, TOKENS / 128), 256, 0, stream>>>(
      xn, Wqkv, bq, bk, bv, nullptr, nullptr, Qb, Kb, Vt,
      TOKENS, 1536, CH, 1.0f, 0, 0, 0);

  const float scl = 0.044194173824159216f;  // 1/sqrt(512)
  if (big) {
    // S = exp(Q K^T * scale), rowsums into lsum
    gemm97<5><<<dim3(HW / 128, HW / 128, 4), 256, 0, stream>>>(
        Qb, Kb, nullptr, nullptr, nullptr, nullptr, lsum, Sb, nullptr, nullptr,
        HW, HW, CH, scl, (size_t)HW * CH, (size_t)HW * CH, (size_t)HW * HW);
    // O = (S V) / lsum, XCD-swizzled 1-D grid
    gemm97<4><<<dim3(512, 1, 1), 256, 0, stream>>>(
        Sb, Vt, nullptr, nullptr, nullptr, nullptr, lsum, Ob, nullptr, nullptr,
        HW, CH, HW, 1.0f, (size_t)HW * HW, (size_t)CH * HW, (size_t)HW * CH);
  } else {
    for (int b = 0; b < 4; ++b) {
      gemm97<5><<<dim3(HW / 128, HW / 128, 1), 256, 0, stream>>>(
          Qb + (size_t)b * HW * CH, Kb + (size_t)b * HW * CH, nullptr, nullptr, nullptr,
          nullptr, lsum + (size_t)b * HW, Sb, nullptr, nullptr,
          HW, HW, CH, scl, 0, 0, 0);
      gemm97<4><<<dim3(4, 32, 1), 256, 0, stream>>>(
          Sb, Vt + (size_t)b * CH * HW, nullptr, nullptr, nullptr, nullptr,
          lsum + (size_t)b * HW, Ob + (size_t)b * HW * CH, nullptr, nullptr,
          HW, CH, HW, 1.0f, 0, 0, 0);
    }
  }

  gemm97<2><<<dim3(CH / 128, TOKENS / 128), 256, 0, stream>>>(
      Ob, WpT, bp, nullptr, nullptr, x, nullptr, out, nullptr, nullptr,
      TOKENS, CH, CH, 1.0f, 0, 0, 0);
}

// Round 5
// 321.055 us; speedup vs baseline: 1.0995x; 1.0995x over previous
//
#include <hip/hip_runtime.h>

typedef unsigned short u16;
typedef short bf16x8 __attribute__((ext_vector_type(8)));
typedef float f32x4 __attribute__((ext_vector_type(4)));

#define CH 512
#define HW 4096
#define TOKENS 16384
#define NGRP 32

__device__ __forceinline__ u16 f2bf(float f) {
  unsigned u = __float_as_uint(f);
  u += 0x7fffu + ((u >> 16) & 1u);   // round-nearest-even
  return (u16)(u >> 16);
}
__device__ __forceinline__ float bf2f(u16 h) {
  return __uint_as_float(((unsigned)h) << 16);
}

// async global->LDS, 16B per lane; lds base must be wave-uniform
#define GLOAD16(gp, lp)                                                        \
  __builtin_amdgcn_global_load_lds(                                            \
      (const __attribute__((address_space(1))) unsigned int*)(const void*)(gp),\
      (__attribute__((address_space(3))) unsigned int*)(void*)(lp), 16, 0, 0)

// ---------------- GroupNorm stats: one block per (b,g) ----------------
__global__ void gn_stats(const float* __restrict__ x, float2* __restrict__ stats) {
  int bg = blockIdx.x;              // 0..127
  int b = bg >> 5, g = bg & 31;
  const float* base = x + (size_t)b * HW * CH + g * 16;
  float s = 0.f, s2 = 0.f;
  for (int p = threadIdx.x; p < HW; p += 256) {
    const float4* row = (const float4*)(base + (size_t)p * CH);
#pragma unroll
    for (int q = 0; q < 4; ++q) {
      float4 v = row[q];
      s += v.x + v.y + v.z + v.w;
      s2 += v.x * v.x + v.y * v.y + v.z * v.z + v.w * v.w;
    }
  }
#pragma unroll
  for (int o = 32; o; o >>= 1) { s += __shfl_down(s, o); s2 += __shfl_down(s2, o); }
  __shared__ float rs[4], rs2[4];
  int wid = threadIdx.x >> 6, lane = threadIdx.x & 63;
  if (lane == 0) { rs[wid] = s; rs2[wid] = s2; }
  __syncthreads();
  if (threadIdx.x == 0) {
    float S = rs[0] + rs[1] + rs[2] + rs[3];
    float S2 = rs2[0] + rs2[1] + rs2[2] + rs2[3];
    float mean = S * (1.f / 65536.f);
    float var = S2 * (1.f / 65536.f) - mean * mean;
    stats[bg] = make_float2(mean, rsqrtf(var + 1e-5f));
  }
}

// ---------------- GroupNorm apply -> xn (bf16) ----------------
__global__ void gn_apply(const float* __restrict__ x, const float* __restrict__ gamma,
                         const float* __restrict__ beta, const float2* __restrict__ stats,
                         u16* __restrict__ xn) {
  size_t i = (size_t)blockIdx.x * blockDim.x + threadIdx.x;  // chunk of 8 elems
  size_t e0 = i * 8;
  int c = (int)(e0 & (CH - 1));
  size_t t = e0 >> 9;
  int b = (int)(t >> 12);
  float2 st = stats[b * NGRP + (c >> 4)];
  float4 v0 = *(const float4*)(x + t * CH + c);
  float4 v1 = *(const float4*)(x + t * CH + c + 4);
  float4 g0 = *(const float4*)(gamma + c);
  float4 g1 = *(const float4*)(gamma + c + 4);
  float4 b0 = *(const float4*)(beta + c);
  float4 b1 = *(const float4*)(beta + c + 4);
  float o[8];
  o[0] = (v0.x - st.x) * st.y * g0.x + b0.x;
  o[1] = (v0.y - st.x) * st.y * g0.y + b0.y;
  o[2] = (v0.z - st.x) * st.y * g0.z + b0.z;
  o[3] = (v0.w - st.x) * st.y * g0.w + b0.w;
  o[4] = (v1.x - st.x) * st.y * g1.x + b1.x;
  o[5] = (v1.y - st.x) * st.y * g1.y + b1.y;
  o[6] = (v1.z - st.x) * st.y * g1.z + b1.z;
  o[7] = (v1.w - st.x) * st.y * g1.w + b1.w;
  union { u16 us[8]; uint4 q; } pk;
#pragma unroll
  for (int k = 0; k < 8; ++k) pk.us[k] = f2bf(o[k]);
  *(uint4*)(xn + e0) = pk.q;
}

// ---------------- transpose 512x512 weights fp32 -> bf16 (T[d][c] = W[c][d]) ----------------
__global__ void transpose_w(const float* __restrict__ W0, const float* __restrict__ W1,
                            const float* __restrict__ W2, const float* __restrict__ W3,
                            u16* __restrict__ T0, u16* __restrict__ T1,
                            u16* __restrict__ T2, u16* __restrict__ T3) {
  const float* W; u16* T;
  switch (blockIdx.z) {
    case 0: W = W0; T = T0; break;
    case 1: W = W1; T = T1; break;
    case 2: W = W2; T = T2; break;
    default: W = W3; T = T3; break;
  }
  __shared__ float tile[32][33];
  int tx = threadIdx.x, ty = threadIdx.y;
  int x0 = blockIdx.x * 32, y0 = blockIdx.y * 32;
#pragma unroll
  for (int r = 0; r < 32; r += 8) tile[ty + r][tx] = W[(size_t)(y0 + ty + r) * CH + x0 + tx];
  __syncthreads();
#pragma unroll
  for (int r = 0; r < 32; r += 8) T[(size_t)(x0 + ty + r) * CH + y0 + tx] = f2bf(tile[tx][ty + r]);
}

// ---- S-GEMM, reg-staged (high-occupancy): S = exp(scale * Q K^T), bf16 out,
// per-(n-block, wave-half) partial rowsums -> lsum[(z*64 + bx*2 + half)*HW + row]
__global__ __launch_bounds__(256) void gemmS(const u16* __restrict__ A,
                                             const u16* __restrict__ Bt,
                                             float* __restrict__ lsum,
                                             u16* __restrict__ Cout,
                                             int M, int N, int K, float scale,
                                             size_t sA, size_t sB, size_t sC) {
  constexpr int BM = 128, BN = 128, BK = 64, LR = 72;
  __shared__ __align__(16) u16 lA[BM * LR];
  __shared__ __align__(16) u16 lB[BN * LR];
  const int z = blockIdx.z;
  A += (size_t)z * sA;
  Bt += (size_t)z * sB;
  const int tid = threadIdx.x;
  const int lane = tid & 63, wid = tid >> 6;
  const int bm = blockIdx.y * BM, bn = blockIdx.x * BN;
  const int wm = (wid >> 1) * 64, wn = (wid & 1) * 64;
  const int r0 = lane & 15, h = lane >> 4;

  f32x4 acc[4][4] = {};

  for (int kt = 0; kt < K; kt += BK) {
    __syncthreads();
#pragma unroll
    for (int s = 0; s < 4; ++s) {
      int cid = tid + s * 256;
      int row = cid >> 3, col = (cid & 7) * 8;
      bf16x8 va = *(const bf16x8*)(A + (size_t)(bm + row) * K + kt + col);
      *(bf16x8*)(&lA[row * LR + col]) = va;
      bf16x8 vb = *(const bf16x8*)(Bt + (size_t)(bn + row) * K + kt + col);
      *(bf16x8*)(&lB[row * LR + col]) = vb;
    }
    __syncthreads();
#pragma unroll
    for (int kk = 0; kk < BK; kk += 32) {
      bf16x8 af[4], bfr[4];
#pragma unroll
      for (int i = 0; i < 4; ++i)
        af[i] = *(const bf16x8*)(&lA[(wm + i * 16 + r0) * LR + kk + h * 8]);
#pragma unroll
      for (int j = 0; j < 4; ++j)
        bfr[j] = *(const bf16x8*)(&lB[(wn + j * 16 + r0) * LR + kk + h * 8]);
#pragma unroll
      for (int i = 0; i < 4; ++i)
#pragma unroll
        for (int j = 0; j < 4; ++j)
          acc[i][j] = __builtin_amdgcn_mfma_f32_16x16x32_bf16(af[i], bfr[j], acc[i][j], 0, 0, 0);
    }
  }

  // epilogue: D layout col(n) = lane&15, row = (lane>>4)*4 + r
  float rsum[4][4];
#pragma unroll
  for (int i = 0; i < 4; ++i)
#pragma unroll
    for (int r = 0; r < 4; ++r) rsum[i][r] = 0.f;
  u16* C = Cout + (size_t)z * sC;
#pragma unroll
  for (int j = 0; j < 4; ++j) {
    int n = bn + wn + j * 16 + r0;
#pragma unroll
    for (int i = 0; i < 4; ++i) {
      int m0 = bm + wm + i * 16 + h * 4;
#pragma unroll
      for (int r = 0; r < 4; ++r) {
        float e = __expf(acc[i][j][r] * scale);
        rsum[i][r] += e;
        C[(size_t)(m0 + r) * N + n] = f2bf(e);
      }
    }
  }
  // reduce over the 16 r0-lanes; one plain store per (half, i, h, r)
  float* lp = lsum + (size_t)(z * 64 + blockIdx.x * 2 + (wid & 1)) * HW;
#pragma unroll
  for (int i = 0; i < 4; ++i)
#pragma unroll
    for (int r = 0; r < 4; ++r) {
#pragma unroll
      for (int w = 1; w < 16; w <<= 1) rsum[i][r] += __shfl_xor(rsum[i][r], w);
      if (r0 == 0) lp[bm + wm + i * 16 + h * 4 + r] = rsum[i][r];
    }
}

// ---- m97-structure NT GEMM: C[M,N] = scale * A[M,K] * Bt[N,K]^T, global_load_lds staging ----
// 128x128 tile, BK=64, 4 waves (2x2), per-wave 4x4 frags of 16x16x32.
// MODE 2: f32 out + residual add (proj)
// MODE 3: fused QKV epilogue (N=1536; chunk 0->Cout, 1->C2 rowmajor, 2->C3 V-layout)
// MODE 4: PV: divide by rowsum (64 partials per row from lsum); XCD-swizzled when gridDim.y==1
template <int MODE>
__global__ __launch_bounds__(256) void gemm97(const u16* __restrict__ A,
                                              const u16* __restrict__ Bt,
                                              const float* __restrict__ bias,
                                              const float* __restrict__ bias2,
                                              const float* __restrict__ bias3,
                                              const float* __restrict__ residual,
                                              const float* __restrict__ lsum,
                                              void* __restrict__ Cout,
                                              void* __restrict__ C2,
                                              void* __restrict__ C3,
                                              int M, int N, int K, float scale,
                                              size_t sA, size_t sB, size_t sC) {
  constexpr int BM = 128, BN = 128, BK = 64;
  __shared__ __align__(16) u16 lA[BM * BK];
  __shared__ __align__(16) u16 lB[BN * BK];
  __shared__ float lsum_sh[(MODE == 4) ? BM : 1];

  int bm, bn, z;
  if constexpr (MODE == 4) {
    if (gridDim.y == 1) {             // big path: 512 blocks, XCD-chunked swizzle
      int p = blockIdx.x;
      int xcd = p & 7, j = p >> 3;    // j: 0..63 per XCD
      int xi = j & 3;                 // 4 consecutive same-XCD blocks share m-panel
      int mp = xcd * 16 + (j >> 2);   // global m-panel 0..127
      bn = xi * BN; bm = (mp & 31) * BM; z = mp >> 5;
    } else {
      z = blockIdx.z; bm = blockIdx.y * BM; bn = blockIdx.x * BN;
    }
  } else {
    z = blockIdx.z; bm = blockIdx.y * BM; bn = blockIdx.x * BN;
  }
  A += (size_t)z * sA;
  Bt += (size_t)z * sB;

  const int tid = threadIdx.x;
  const int lane = tid & 63, wid = tid >> 6;
  const int wm = (wid >> 1) * 64, wn = (wid & 1) * 64;
  const int r0 = lane & 15, h = lane >> 4;

  if constexpr (MODE == 4) {
    // pre-pass: row sums = sum of 64 partials per row (written by gemmS)
    if (tid < BM) {
      const float* lp = lsum + (size_t)(z * 64) * HW + bm + tid;
      float s = 0.f;
#pragma unroll 8
      for (int p = 0; p < 64; ++p) s += lp[(size_t)p * HW];
      lsum_sh[tid] = s;
    }
  }

  // staging geometry: wave wid, issue s stages 8 rows x 64 cols (1 KB) of each tile
  const int srow = lane >> 3, scol = (lane & 7) * 8;
  size_t aoff[4], boff[4];
#pragma unroll
  for (int s = 0; s < 4; ++s) {
    int row = (wid * 4 + s) * 8 + srow;
    aoff[s] = (size_t)(bm + row) * K + scol;
    boff[s] = (size_t)(bn + row) * K + scol;
  }

  f32x4 acc[4][4] = {};

  for (int kt = 0; kt < K; kt += BK) {
    __syncthreads();
#pragma unroll
    for (int s = 0; s < 4; ++s) {
      GLOAD16(A + aoff[s] + kt, &lA[(wid * 4 + s) * 512]);
      GLOAD16(Bt + boff[s] + kt, &lB[(wid * 4 + s) * 512]);
    }
    __syncthreads();
#pragma unroll
    for (int kk = 0; kk < BK; kk += 32) {
      bf16x8 af[4], bfr[4];
#pragma unroll
      for (int i = 0; i < 4; ++i)
        af[i] = *(const bf16x8*)(&lA[(wm + i * 16 + r0) * BK + kk + h * 8]);
#pragma unroll
      for (int j = 0; j < 4; ++j)
        bfr[j] = *(const bf16x8*)(&lB[(wn + j * 16 + r0) * BK + kk + h * 8]);
#pragma unroll
      for (int i = 0; i < 4; ++i)
#pragma unroll
        for (int j = 0; j < 4; ++j)
          acc[i][j] = __builtin_amdgcn_mfma_f32_16x16x32_bf16(af[i], bfr[j], acc[i][j], 0, 0, 0);
    }
  }

  // epilogue: D layout col = lane&15 (n), row = (lane>>4)*4 + r
#pragma unroll
  for (int j = 0; j < 4; ++j) {
    int n = bn + wn + j * 16 + r0;
    float bvv;
    if constexpr (MODE == 3) {
      int nn = n & 511, ch = n >> 9;
      bvv = ch == 0 ? bias[nn] : ch == 1 ? bias2[nn] : bias3[nn];
    } else {
      bvv = bias ? bias[n] : 0.0f;
    }
#pragma unroll
    for (int i = 0; i < 4; ++i) {
      int m0 = bm + wm + i * 16 + h * 4;
      float v[4];
#pragma unroll
      for (int r = 0; r < 4; ++r) v[r] = acc[i][j][r] * scale + bvv;
      if constexpr (MODE == 2) {
        float* C = (float*)Cout + (size_t)z * sC;
#pragma unroll
        for (int r = 0; r < 4; ++r) {
          size_t idx = (size_t)(m0 + r) * N + n;
          C[idx] = v[r] + residual[idx];
        }
      } else if constexpr (MODE == 3) {
        int nn = n & 511, ch = n >> 9;
        if (ch == 2) {                // V: transposed layout [bb][CH][HW]
          int bb = m0 >> 12, tl = m0 & (HW - 1);
          u16* C = (u16*)C3 + ((size_t)bb * CH + nn) * HW + tl;
          union { u16 us[4]; uint2 q; } pk;
#pragma unroll
          for (int r = 0; r < 4; ++r) pk.us[r] = f2bf(v[r]);
          *(uint2*)C = pk.q;
        } else {
          u16* C = (u16*)(ch == 0 ? Cout : C2);
#pragma unroll
          for (int r = 0; r < 4; ++r) C[(size_t)(m0 + r) * CH + nn] = f2bf(v[r]);
        }
      } else {                        // MODE 4: PV, divide by row sum
        u16* C = (u16*)Cout + (size_t)z * sC;
#pragma unroll
        for (int r = 0; r < 4; ++r) {
          float inv = 1.0f / lsum_sh[wm + i * 16 + h * 4 + r];
          C[(size_t)(m0 + r) * N + n] = f2bf(v[r] * inv);
        }
      }
    }
  }
}

extern "C" void kernel_launch(void* const* d_in, const int* in_sizes, int n_in,
                              void* d_out, int out_size, void* d_ws, size_t ws_size,
                              hipStream_t stream) {
  (void)in_sizes; (void)n_in; (void)out_size;
  const float* x     = (const float*)d_in[0];
  const float* gamma = (const float*)d_in[1];
  const float* beta  = (const float*)d_in[2];
  const float* Wq    = (const float*)d_in[3];
  const float* bq    = (const float*)d_in[4];
  const float* Wk    = (const float*)d_in[5];
  const float* bk    = (const float*)d_in[6];
  const float* Wv    = (const float*)d_in[7];
  const float* bv    = (const float*)d_in[8];
  const float* Wp    = (const float*)d_in[9];
  const float* bp    = (const float*)d_in[10];
  float* out = (float*)d_out;

  char* ws = (char*)d_ws;
  size_t off = 0;
  auto alloc = [&](size_t bytes) -> void* {
    void* p = ws + off;
    off += (bytes + 255) & ~(size_t)255;
    return p;
  };
  const size_t XN = (size_t)TOKENS * CH * 2;      // 16 MB
  const size_t WT = (size_t)CH * CH * 2;          // 0.5 MB
  const size_t SBB = (size_t)HW * HW * 2;         // 33.5 MB per batch
  const size_t LS = (size_t)4 * 64 * HW * sizeof(float);  // 4 MB partial rowsums
  const size_t need_all = 1024 * 1024 + LS + 5 * XN + 4 * WT + 4 * SBB;
  const bool big = ws_size >= need_all;           // deterministic across calls

  float2* stats = (float2*)alloc(128 * sizeof(float2));
  float* lsum_part = (float*)alloc(LS);           // [z][64][HW]
  u16* xn   = (u16*)alloc(XN);
  u16* Qb   = (u16*)alloc(XN);
  u16* Kb   = (u16*)alloc(XN);
  u16* Vt   = (u16*)alloc(XN);   // [B][CH][HW]
  u16* Ob   = (u16*)alloc(XN);
  u16* Wqkv = (u16*)alloc(3 * WT);  // [Wq^T; Wk^T; Wv^T] stacked along rows
  u16* WpT  = (u16*)alloc(WT);
  u16* Sb   = (u16*)alloc(big ? 4 * SBB : SBB);   // exp'd scores

  gn_stats<<<128, 256, 0, stream>>>(x, stats);
  gn_apply<<<TOKENS * CH / 8 / 256, 256, 0, stream>>>(x, gamma, beta, stats, xn);
  transpose_w<<<dim3(16, 16, 4), dim3(32, 8), 0, stream>>>(
      Wq, Wk, Wv, Wp, Wqkv, Wqkv + (size_t)CH * CH, Wqkv + 2 * (size_t)CH * CH, WpT);

  // fused QKV: one GEMM, N=1536, epilogue routes chunks
  gemm97<3><<<dim3(1536 / 128, TOKENS / 128), 256, 0, stream>>>(
      xn, Wqkv, bq, bk, bv, nullptr, nullptr, Qb, Kb, Vt,
      TOKENS, 1536, CH, 1.0f, 0, 0, 0);

  const float scl = 0.044194173824159216f;  // 1/sqrt(512)
  if (big) {
    // S = exp(Q K^T * scale), partial rowsums into lsum_part (no atomics)
    gemmS<<<dim3(HW / 128, HW / 128, 4), 256, 0, stream>>>(
        Qb, Kb, lsum_part, Sb,
        HW, HW, CH, scl, (size_t)HW * CH, (size_t)HW * CH, (size_t)HW * HW);
    // O = (S V) / rowsum, XCD-swizzled 1-D grid
    gemm97<4><<<dim3(512, 1, 1), 256, 0, stream>>>(
        Sb, Vt, nullptr, nullptr, nullptr, nullptr, lsum_part, Ob, nullptr, nullptr,
        HW, CH, HW, 1.0f, (size_t)HW * HW, (size_t)CH * HW, (size_t)HW * CH);
  } else {
    for (int b = 0; b < 4; ++b) {
      gemmS<<<dim3(HW / 128, HW / 128, 1), 256, 0, stream>>>(
          Qb + (size_t)b * HW * CH, Kb + (size_t)b * HW * CH,
          lsum_part + (size_t)b * 64 * HW, Sb, HW, HW, CH, scl, 0, 0, 0);
      gemm97<4><<<dim3(4, 32, 1), 256, 0, stream>>>(
          Sb, Vt + (size_t)b * CH * HW, nullptr, nullptr, nullptr, nullptr,
          lsum_part + (size_t)b * 64 * HW, Ob + (size_t)b * HW * CH, nullptr, nullptr,
          HW, CH, HW, 1.0f, 0, 0, 0);
    }
  }

  gemm97<2><<<dim3(CH / 128, TOKENS / 128), 256, 0, stream>>>(
      Ob, WpT, bp, nullptr, nullptr, x, nullptr, out, nullptr, nullptr,
      TOKENS, CH, CH, 1.0f, 0, 0, 0);
}

// Round 6
// 246.587 us; speedup vs baseline: 1.4315x; 1.3020x over previous
//
#include <hip/hip_runtime.h>

typedef unsigned short u16;
typedef unsigned char u8;
typedef short bf16x8 __attribute__((ext_vector_type(8)));
typedef float f32x4 __attribute__((ext_vector_type(4)));

#define CH 512
#define HW 4096
#define TOKENS 16384
#define NGRP 32

__device__ __forceinline__ u16 f2bf(float f) {
  unsigned u = __float_as_uint(f);
  u += 0x7fffu + ((u >> 16) & 1u);   // round-nearest-even
  return (u16)(u >> 16);
}
__device__ __forceinline__ float bf2f(u16 h) {
  return __uint_as_float(((unsigned)h) << 16);
}
__device__ __forceinline__ u8 f2fp8(float f) {   // OCP e4m3fn, RNE+sat
  return (u8)(__builtin_amdgcn_cvt_pk_fp8_f32(f, f, 0, false) & 0xff);
}
__device__ __forceinline__ unsigned f2fp8x4(float a, float b, float c, float d) {
  int lo = __builtin_amdgcn_cvt_pk_fp8_f32(a, b, 0, false);
  return (unsigned)__builtin_amdgcn_cvt_pk_fp8_f32(c, d, lo, true);
}

// async global->LDS, 16B per lane; lds base must be wave-uniform
#define GLOAD16(gp, lp)                                                        \
  __builtin_amdgcn_global_load_lds(                                            \
      (const __attribute__((address_space(1))) unsigned int*)(const void*)(gp),\
      (__attribute__((address_space(3))) unsigned int*)(void*)(lp), 16, 0, 0)

// ---------------- GroupNorm stats: one block per (b,g) ----------------
__global__ void gn_stats(const float* __restrict__ x, float2* __restrict__ stats) {
  int bg = blockIdx.x;              // 0..127
  int b = bg >> 5, g = bg & 31;
  const float* base = x + (size_t)b * HW * CH + g * 16;
  float s = 0.f, s2 = 0.f;
  for (int p = threadIdx.x; p < HW; p += 256) {
    const float4* row = (const float4*)(base + (size_t)p * CH);
#pragma unroll
    for (int q = 0; q < 4; ++q) {
      float4 v = row[q];
      s += v.x + v.y + v.z + v.w;
      s2 += v.x * v.x + v.y * v.y + v.z * v.z + v.w * v.w;
    }
  }
#pragma unroll
  for (int o = 32; o; o >>= 1) { s += __shfl_down(s, o); s2 += __shfl_down(s2, o); }
  __shared__ float rs[4], rs2[4];
  int wid = threadIdx.x >> 6, lane = threadIdx.x & 63;
  if (lane == 0) { rs[wid] = s; rs2[wid] = s2; }
  __syncthreads();
  if (threadIdx.x == 0) {
    float S = rs[0] + rs[1] + rs[2] + rs[3];
    float S2 = rs2[0] + rs2[1] + rs2[2] + rs2[3];
    float mean = S * (1.f / 65536.f);
    float var = S2 * (1.f / 65536.f) - mean * mean;
    stats[bg] = make_float2(mean, rsqrtf(var + 1e-5f));
  }
}

// ---------------- GroupNorm apply -> xn (bf16) ----------------
__global__ void gn_apply(const float* __restrict__ x, const float* __restrict__ gamma,
                         const float* __restrict__ beta, const float2* __restrict__ stats,
                         u16* __restrict__ xn) {
  size_t i = (size_t)blockIdx.x * blockDim.x + threadIdx.x;  // chunk of 8 elems
  size_t e0 = i * 8;
  int c = (int)(e0 & (CH - 1));
  size_t t = e0 >> 9;
  int b = (int)(t >> 12);
  float2 st = stats[b * NGRP + (c >> 4)];
  float4 v0 = *(const float4*)(x + t * CH + c);
  float4 v1 = *(const float4*)(x + t * CH + c + 4);
  float4 g0 = *(const float4*)(gamma + c);
  float4 g1 = *(const float4*)(gamma + c + 4);
  float4 b0 = *(const float4*)(beta + c);
  float4 b1 = *(const float4*)(beta + c + 4);
  float o[8];
  o[0] = (v0.x - st.x) * st.y * g0.x + b0.x;
  o[1] = (v0.y - st.x) * st.y * g0.y + b0.y;
  o[2] = (v0.z - st.x) * st.y * g0.z + b0.z;
  o[3] = (v0.w - st.x) * st.y * g0.w + b0.w;
  o[4] = (v1.x - st.x) * st.y * g1.x + b1.x;
  o[5] = (v1.y - st.x) * st.y * g1.y + b1.y;
  o[6] = (v1.z - st.x) * st.y * g1.z + b1.z;
  o[7] = (v1.w - st.x) * st.y * g1.w + b1.w;
  union { u16 us[8]; uint4 q; } pk;
#pragma unroll
  for (int k = 0; k < 8; ++k) pk.us[k] = f2bf(o[k]);
  *(uint4*)(xn + e0) = pk.q;
}

// ---------------- transpose 512x512 weights fp32 -> bf16 (T[d][c] = W[c][d]) ----------------
__global__ void transpose_w(const float* __restrict__ W0, const float* __restrict__ W1,
                            const float* __restrict__ W2, const float* __restrict__ W3,
                            u16* __restrict__ T0, u16* __restrict__ T1,
                            u16* __restrict__ T2, u16* __restrict__ T3) {
  const float* W; u16* T;
  switch (blockIdx.z) {
    case 0: W = W0; T = T0; break;
    case 1: W = W1; T = T1; break;
    case 2: W = W2; T = T2; break;
    default: W = W3; T = T3; break;
  }
  __shared__ float tile[32][33];
  int tx = threadIdx.x, ty = threadIdx.y;
  int x0 = blockIdx.x * 32, y0 = blockIdx.y * 32;
#pragma unroll
  for (int r = 0; r < 32; r += 8) tile[ty + r][tx] = W[(size_t)(y0 + ty + r) * CH + x0 + tx];
  __syncthreads();
#pragma unroll
  for (int r = 0; r < 32; r += 8) T[(size_t)(x0 + ty + r) * CH + y0 + tx] = f2bf(tile[tx][ty + r]);
}

// ---- QKV: bf16 m97 GEMM (global_load_lds), epilogue -> fp8 Q8,K8 rowmajor + V8t transposed ----
__global__ __launch_bounds__(256) void qkv97(const u16* __restrict__ A,
                                             const u16* __restrict__ Bt,
                                             const float* __restrict__ bq,
                                             const float* __restrict__ bk,
                                             const float* __restrict__ bv,
                                             u8* __restrict__ Q8, u8* __restrict__ K8,
                                             u8* __restrict__ V8t) {
  constexpr int BM = 128, BN = 128, BK = 64;
  const int K = CH;
  __shared__ __align__(16) u16 lA[BM * BK];
  __shared__ __align__(16) u16 lB[BN * BK];
  const int tid = threadIdx.x;
  const int lane = tid & 63, wid = tid >> 6;
  const int bm = blockIdx.y * BM, bn = blockIdx.x * BN;
  const int wm = (wid >> 1) * 64, wn = (wid & 1) * 64;
  const int r0 = lane & 15, h = lane >> 4;

  const int srow = lane >> 3, scol = (lane & 7) * 8;
  size_t aoff[4], boff[4];
#pragma unroll
  for (int s = 0; s < 4; ++s) {
    int row = (wid * 4 + s) * 8 + srow;
    aoff[s] = (size_t)(bm + row) * K + scol;
    boff[s] = (size_t)(bn + row) * K + scol;
  }

  f32x4 acc[4][4] = {};
  for (int kt = 0; kt < K; kt += BK) {
    __syncthreads();
#pragma unroll
    for (int s = 0; s < 4; ++s) {
      GLOAD16(A + aoff[s] + kt, &lA[(wid * 4 + s) * 512]);
      GLOAD16(Bt + boff[s] + kt, &lB[(wid * 4 + s) * 512]);
    }
    __syncthreads();
#pragma unroll
    for (int kk = 0; kk < BK; kk += 32) {
      bf16x8 af[4], bfr[4];
#pragma unroll
      for (int i = 0; i < 4; ++i)
        af[i] = *(const bf16x8*)(&lA[(wm + i * 16 + r0) * BK + kk + h * 8]);
#pragma unroll
      for (int j = 0; j < 4; ++j)
        bfr[j] = *(const bf16x8*)(&lB[(wn + j * 16 + r0) * BK + kk + h * 8]);
#pragma unroll
      for (int i = 0; i < 4; ++i)
#pragma unroll
        for (int j = 0; j < 4; ++j)
          acc[i][j] = __builtin_amdgcn_mfma_f32_16x16x32_bf16(af[i], bfr[j], acc[i][j], 0, 0, 0);
    }
  }

#pragma unroll
  for (int j = 0; j < 4; ++j) {
    int n = bn + wn + j * 16 + r0;
    int nn = n & 511, ch = n >> 9;
    float bvv = ch == 0 ? bq[nn] : ch == 1 ? bk[nn] : bv[nn];
#pragma unroll
    for (int i = 0; i < 4; ++i) {
      int m0 = bm + wm + i * 16 + h * 4;
      float v[4];
#pragma unroll
      for (int r = 0; r < 4; ++r) v[r] = acc[i][j][r] + bvv;
      if (ch == 2) {                  // V: transposed fp8 [bb][CH][HW], pack 4 rows
        int bb = m0 >> 12, tl = m0 & (HW - 1);
        *(unsigned*)(V8t + ((size_t)bb * CH + nn) * HW + tl) =
            f2fp8x4(v[0], v[1], v[2], v[3]);
      } else {
        u8* P = ch == 0 ? Q8 : K8;
#pragma unroll
        for (int r = 0; r < 4; ++r) P[(size_t)(m0 + r) * CH + nn] = f2fp8(v[r]);
      }
    }
  }
}

// ---- S-GEMM fp8: S8 = fp8(exp(scale * Q8 K8^T)), partial rowsums (f32, pre-quant) ----
// reg-staged, LDS row stride 80B (16B-aligned writes, <=2-way bank alias on b64 reads)
__global__ __launch_bounds__(256) void sgemm8(const u8* __restrict__ A,
                                              const u8* __restrict__ Bt,
                                              float* __restrict__ lsum,
                                              u8* __restrict__ S8,
                                              int M, int N, int K, float scale,
                                              size_t sA, size_t sB, size_t sC) {
  constexpr int BM = 128, BN = 128, BK = 64, LRB = 80;
  __shared__ __align__(16) u8 lA[BM * LRB];
  __shared__ __align__(16) u8 lB[BN * LRB];
  const int z = blockIdx.z;
  A += (size_t)z * sA;
  Bt += (size_t)z * sB;
  const int tid = threadIdx.x;
  const int lane = tid & 63, wid = tid >> 6;
  const int bm = blockIdx.y * BM, bn = blockIdx.x * BN;
  const int wm = (wid >> 1) * 64, wn = (wid & 1) * 64;
  const int r0 = lane & 15, h = lane >> 4;

  f32x4 acc[4][4] = {};
  for (int kt = 0; kt < K; kt += BK) {
    __syncthreads();
#pragma unroll
    for (int s = 0; s < 2; ++s) {
      int cid = tid + s * 256;
      int row = cid >> 2, col = (cid & 3) * 16;
      *(uint4*)(&lA[row * LRB + col]) =
          *(const uint4*)(A + (size_t)(bm + row) * K + kt + col);
      *(uint4*)(&lB[row * LRB + col]) =
          *(const uint4*)(Bt + (size_t)(bn + row) * K + kt + col);
    }
    __syncthreads();
#pragma unroll
    for (int kk = 0; kk < BK; kk += 32) {
      long af[4], bfr[4];
#pragma unroll
      for (int i = 0; i < 4; ++i)
        af[i] = *(const long*)(&lA[(wm + i * 16 + r0) * LRB + kk + h * 8]);
#pragma unroll
      for (int j = 0; j < 4; ++j)
        bfr[j] = *(const long*)(&lB[(wn + j * 16 + r0) * LRB + kk + h * 8]);
#pragma unroll
      for (int i = 0; i < 4; ++i)
#pragma unroll
        for (int j = 0; j < 4; ++j)
          acc[i][j] = __builtin_amdgcn_mfma_f32_16x16x32_fp8_fp8(af[i], bfr[j], acc[i][j], 0, 0, 0);
    }
  }

  // epilogue: D layout col(n) = lane&15, row = (lane>>4)*4 + r; i-outer keeps 4 rsum regs
  u8* C = S8 + (size_t)z * sC;
  float* lp = lsum + (size_t)(z * 64 + blockIdx.x * 2 + (wid & 1)) * HW;
#pragma unroll
  for (int i = 0; i < 4; ++i) {
    int m0 = bm + wm + i * 16 + h * 4;
    float rs[4] = {0.f, 0.f, 0.f, 0.f};
#pragma unroll
    for (int j = 0; j < 4; ++j) {
      int n = bn + wn + j * 16 + r0;
#pragma unroll
      for (int r = 0; r < 4; ++r) {
        float e = __expf(acc[i][j][r] * scale);
        rs[r] += e;
        C[(size_t)(m0 + r) * N + n] = f2fp8(e);
      }
    }
#pragma unroll
    for (int r = 0; r < 4; ++r) {
#pragma unroll
      for (int w = 1; w < 16; w <<= 1) rs[r] += __shfl_xor(rs[r], w);
      if (r0 == 0) lp[m0 + r] = rs[r];
    }
  }
}

// ---- PV fp8: Ob = (S8 V8t^T) / rowsum, bf16 out; XCD-swizzled when gridDim.y==1 ----
__global__ __launch_bounds__(256) void pv8(const u8* __restrict__ A,
                                           const u8* __restrict__ Bt,
                                           const float* __restrict__ lsum,
                                           u16* __restrict__ Ob,
                                           int M, int N, int K,
                                           size_t sA, size_t sB, size_t sC) {
  constexpr int BM = 128, BN = 128, BK = 64, LRB = 80;
  __shared__ __align__(16) u8 lA[BM * LRB];
  __shared__ __align__(16) u8 lB[BN * LRB];
  __shared__ float lsum_sh[BM];

  int bm, bn, z;
  if (gridDim.y == 1) {               // big path: 512 blocks, XCD-chunked swizzle
    int p = blockIdx.x;
    int xcd = p & 7, j = p >> 3;      // j: 0..63 per XCD
    int xi = j & 3;                   // 4 consecutive same-XCD blocks share m-panel
    int mp = xcd * 16 + (j >> 2);     // global m-panel 0..127
    bn = xi * BN; bm = (mp & 31) * BM; z = mp >> 5;
  } else {
    z = blockIdx.z; bm = blockIdx.y * BM; bn = blockIdx.x * BN;
  }
  A += (size_t)z * sA;
  Bt += (size_t)z * sB;
  const int tid = threadIdx.x;
  const int lane = tid & 63, wid = tid >> 6;
  const int wm = (wid >> 1) * 64, wn = (wid & 1) * 64;
  const int r0 = lane & 15, h = lane >> 4;

  // pre-pass: true row sums = sum of 64 partials per row
  if (tid < BM) {
    const float* lp = lsum + (size_t)(z * 64) * HW + bm + tid;
    float s = 0.f;
#pragma unroll 8
    for (int p = 0; p < 64; ++p) s += lp[(size_t)p * HW];
    lsum_sh[tid] = s;
  }

  f32x4 acc[4][4] = {};
  for (int kt = 0; kt < K; kt += BK) {
    __syncthreads();
#pragma unroll
    for (int s = 0; s < 2; ++s) {
      int cid = tid + s * 256;
      int row = cid >> 2, col = (cid & 3) * 16;
      *(uint4*)(&lA[row * LRB + col]) =
          *(const uint4*)(A + (size_t)(bm + row) * K + kt + col);
      *(uint4*)(&lB[row * LRB + col]) =
          *(const uint4*)(Bt + (size_t)(bn + row) * K + kt + col);
    }
    __syncthreads();
#pragma unroll
    for (int kk = 0; kk < BK; kk += 32) {
      long af[4], bfr[4];
#pragma unroll
      for (int i = 0; i < 4; ++i)
        af[i] = *(const long*)(&lA[(wm + i * 16 + r0) * LRB + kk + h * 8]);
#pragma unroll
      for (int j = 0; j < 4; ++j)
        bfr[j] = *(const long*)(&lB[(wn + j * 16 + r0) * LRB + kk + h * 8]);
#pragma unroll
      for (int i = 0; i < 4; ++i)
#pragma unroll
        for (int j = 0; j < 4; ++j)
          acc[i][j] = __builtin_amdgcn_mfma_f32_16x16x32_fp8_fp8(af[i], bfr[j], acc[i][j], 0, 0, 0);
    }
  }

  u16* C = Ob + (size_t)z * sC;
#pragma unroll
  for (int j = 0; j < 4; ++j) {
    int n = bn + wn + j * 16 + r0;
#pragma unroll
    for (int i = 0; i < 4; ++i) {
      int m0 = bm + wm + i * 16 + h * 4;
#pragma unroll
      for (int r = 0; r < 4; ++r) {
        float inv = 1.0f / lsum_sh[wm + i * 16 + h * 4 + r];
        C[(size_t)(m0 + r) * N + n] = f2bf(acc[i][j][r] * inv);
      }
    }
  }
}

// ---- proj: bf16 m97 GEMM, f32 out + residual ----
__global__ __launch_bounds__(256) void proj97(const u16* __restrict__ A,
                                              const u16* __restrict__ Bt,
                                              const float* __restrict__ bias,
                                              const float* __restrict__ residual,
                                              float* __restrict__ Cout) {
  constexpr int BM = 128, BN = 128, BK = 64;
  const int K = CH, N = CH;
  __shared__ __align__(16) u16 lA[BM * BK];
  __shared__ __align__(16) u16 lB[BN * BK];
  const int tid = threadIdx.x;
  const int lane = tid & 63, wid = tid >> 6;
  const int bm = blockIdx.y * BM, bn = blockIdx.x * BN;
  const int wm = (wid >> 1) * 64, wn = (wid & 1) * 64;
  const int r0 = lane & 15, h = lane >> 4;

  const int srow = lane >> 3, scol = (lane & 7) * 8;
  size_t aoff[4], boff[4];
#pragma unroll
  for (int s = 0; s < 4; ++s) {
    int row = (wid * 4 + s) * 8 + srow;
    aoff[s] = (size_t)(bm + row) * K + scol;
    boff[s] = (size_t)(bn + row) * K + scol;
  }

  f32x4 acc[4][4] = {};
  for (int kt = 0; kt < K; kt += BK) {
    __syncthreads();
#pragma unroll
    for (int s = 0; s < 4; ++s) {
      GLOAD16(A + aoff[s] + kt, &lA[(wid * 4 + s) * 512]);
      GLOAD16(Bt + boff[s] + kt, &lB[(wid * 4 + s) * 512]);
    }
    __syncthreads();
#pragma unroll
    for (int kk = 0; kk < BK; kk += 32) {
      bf16x8 af[4], bfr[4];
#pragma unroll
      for (int i = 0; i < 4; ++i)
        af[i] = *(const bf16x8*)(&lA[(wm + i * 16 + r0) * BK + kk + h * 8]);
#pragma unroll
      for (int j = 0; j < 4; ++j)
        bfr[j] = *(const bf16x8*)(&lB[(wn + j * 16 + r0) * BK + kk + h * 8]);
#pragma unroll
      for (int i = 0; i < 4; ++i)
#pragma unroll
        for (int j = 0; j < 4; ++j)
          acc[i][j] = __builtin_amdgcn_mfma_f32_16x16x32_bf16(af[i], bfr[j], acc[i][j], 0, 0, 0);
    }
  }

#pragma unroll
  for (int j = 0; j < 4; ++j) {
    int n = bn + wn + j * 16 + r0;
    float bvv = bias[n];
#pragma unroll
    for (int i = 0; i < 4; ++i) {
      int m0 = bm + wm + i * 16 + h * 4;
#pragma unroll
      for (int r = 0; r < 4; ++r) {
        size_t idx = (size_t)(m0 + r) * N + n;
        Cout[idx] = acc[i][j][r] + bvv + residual[idx];
      }
    }
  }
}

extern "C" void kernel_launch(void* const* d_in, const int* in_sizes, int n_in,
                              void* d_out, int out_size, void* d_ws, size_t ws_size,
                              hipStream_t stream) {
  (void)in_sizes; (void)n_in; (void)out_size;
  const float* x     = (const float*)d_in[0];
  const float* gamma = (const float*)d_in[1];
  const float* beta  = (const float*)d_in[2];
  const float* Wq    = (const float*)d_in[3];
  const float* bq    = (const float*)d_in[4];
  const float* Wk    = (const float*)d_in[5];
  const float* bk    = (const float*)d_in[6];
  const float* Wv    = (const float*)d_in[7];
  const float* bv    = (const float*)d_in[8];
  const float* Wp    = (const float*)d_in[9];
  const float* bp    = (const float*)d_in[10];
  float* out = (float*)d_out;

  char* ws = (char*)d_ws;
  size_t off = 0;
  auto alloc = [&](size_t bytes) -> void* {
    void* p = ws + off;
    off += (bytes + 255) & ~(size_t)255;
    return p;
  };
  const size_t XN  = (size_t)TOKENS * CH * 2;     // 16 MB bf16
  const size_t X8  = (size_t)TOKENS * CH;         // 8 MB fp8
  const size_t WT  = (size_t)CH * CH * 2;         // 0.5 MB
  const size_t S8B = (size_t)HW * HW;             // 16.8 MB fp8 per batch
  const size_t LS  = (size_t)4 * 64 * HW * sizeof(float);  // 4 MB partial rowsums
  const size_t need_all = 1024 * 1024 + LS + 2 * XN + 3 * X8 + 4 * WT + 4 * S8B;
  const bool big = ws_size >= need_all;           // deterministic across calls

  float2* stats    = (float2*)alloc(128 * sizeof(float2));
  float* lsum_part = (float*)alloc(LS);           // [z][64][HW]
  u16* xn   = (u16*)alloc(XN);
  u16* Ob   = (u16*)alloc(XN);
  u8*  Q8   = (u8*)alloc(X8);    // [B*HW][CH] fp8
  u8*  K8   = (u8*)alloc(X8);
  u8*  V8t  = (u8*)alloc(X8);    // [B][CH][HW] fp8
  u16* Wqkv = (u16*)alloc(3 * WT);  // [Wq^T; Wk^T; Wv^T] stacked along rows
  u16* WpT  = (u16*)alloc(WT);
  u8*  S8   = (u8*)alloc(big ? 4 * S8B : S8B);    // exp'd scores fp8

  gn_stats<<<128, 256, 0, stream>>>(x, stats);
  gn_apply<<<TOKENS * CH / 8 / 256, 256, 0, stream>>>(x, gamma, beta, stats, xn);
  transpose_w<<<dim3(16, 16, 4), dim3(32, 8), 0, stream>>>(
      Wq, Wk, Wv, Wp, Wqkv, Wqkv + (size_t)CH * CH, Wqkv + 2 * (size_t)CH * CH, WpT);

  qkv97<<<dim3(1536 / 128, TOKENS / 128), 256, 0, stream>>>(
      xn, Wqkv, bq, bk, bv, Q8, K8, V8t);

  const float scl = 0.044194173824159216f;  // 1/sqrt(512)
  if (big) {
    sgemm8<<<dim3(HW / 128, HW / 128, 4), 256, 0, stream>>>(
        Q8, K8, lsum_part, S8, HW, HW, CH, scl,
        (size_t)HW * CH, (size_t)HW * CH, (size_t)HW * HW);
    pv8<<<dim3(512, 1, 1), 256, 0, stream>>>(
        S8, V8t, lsum_part, Ob, HW, CH, HW,
        (size_t)HW * HW, (size_t)CH * HW, (size_t)HW * CH);
  } else {
    for (int b = 0; b < 4; ++b) {
      sgemm8<<<dim3(HW / 128, HW / 128, 1), 256, 0, stream>>>(
          Q8 + (size_t)b * HW * CH, K8 + (size_t)b * HW * CH,
          lsum_part + (size_t)b * 64 * HW, S8, HW, HW, CH, scl, 0, 0, 0);
      pv8<<<dim3(4, 32, 1), 256, 0, stream>>>(
          S8, V8t + (size_t)b * CH * HW, lsum_part + (size_t)b * 64 * HW,
          Ob + (size_t)b * HW * CH, HW, CH, HW, 0, 0, 0);
    }
  }

  proj97<<<dim3(CH / 128, TOKENS / 128), 256, 0, stream>>>(Ob, WpT, bp, x, out);
}